// Round 13
// baseline (340.537 us; speedup 1.0000x reference)
//
#include <hip/hip_runtime.h>
#include <hip/hip_cooperative_groups.h>
#include <math.h>

// MultiHeadGAT fused pipeline, round 13.
// Front: R8 exact (kconv fused T+W; k1 = R4 champion + L2E prescale, 39.9us).
// Tail: SINGLE cooperative kernel (512 blocks, grid.sync between stages)
//       replacing 6 launches: lse -> colsum+wsum -> cat -> ln -> fcs -> red.
//       Attacks the ~21us of launch gaps measured across rounds.

namespace cg = cooperative_groups;

#define NH   4
#define TD   768
#define HID  256
#define OD   768
#define BB   16
#define LL   1024
#define RTOT (BB*LL)   // 16384 rows per head
#define L2E  1.4426950408889634f

typedef __attribute__((ext_vector_type(8))) short bf16x8;
typedef __attribute__((ext_vector_type(4))) float f32x4;

#if __has_builtin(__builtin_amdgcn_exp2f)
#define EXP2(x) __builtin_amdgcn_exp2f(x)
#else
#define EXP2(x) __expf((x) * 0.6931471805599453f)
#endif
#if __has_builtin(__builtin_amdgcn_logf)
#define LOG2(x) __builtin_amdgcn_logf(x)
#else
#define LOG2(x) (__logf(x) * L2E)
#endif

__device__ __forceinline__ float lrelu(float x) { return fmaxf(x, 0.01f * x); }

__device__ __forceinline__ float waveReduceSum(float v) {
  #pragma unroll
  for (int m = 1; m < 64; m <<= 1) v += __shfl_xor(v, m, 64);
  return v;
}
__device__ __forceinline__ float waveReduceMax(float v) {
  #pragma unroll
  for (int m = 1; m < 64; m <<= 1) v = fmaxf(v, __shfl_xor(v, m, 64));
  return v;
}
__device__ __forceinline__ float red16(float v) {   // reduce across 16-lane group
  v += __shfl_xor(v, 1, 64); v += __shfl_xor(v, 2, 64);
  v += __shfl_xor(v, 4, 64); v += __shfl_xor(v, 8, 64);
  return v;
}

__device__ __forceinline__ unsigned short f2b(float f) {  // f32 -> bf16 RNE
  union { float f; unsigned u; } v; v.f = f;
  unsigned u = v.u;
  return (unsigned short)((u + 0x7fffu + ((u >> 16) & 1u)) >> 16);
}
__device__ __forceinline__ float b2f(unsigned short h) {
  union { unsigned u; float f; } v; v.u = ((unsigned)h) << 16;
  return v.f;
}

__device__ __forceinline__ void gll16(const void* g, void* l) {
  __builtin_amdgcn_global_load_lds(
      (const __attribute__((address_space(1))) unsigned int*)g,
      (__attribute__((address_space(3))) unsigned int*)l, 16, 0, 0);
}

// ---- fused conversion kernel ----------------------------------------------
__global__ __launch_bounds__(256) void kconv(const float* __restrict__ T,
                                             const float* __restrict__ Wfc,
                                             unsigned short* __restrict__ Tb,
                                             unsigned short* __restrict__ Wtb) {
  __shared__ float tile[64][65];
  const int t = threadIdx.x;
  if (blockIdx.x < 6144) {
    const size_t i = ((size_t)blockIdx.x * 256 + t) * 8;
    const float4 a = *(const float4*)(T + i);
    const float4 b = *(const float4*)(T + i + 4);
    bf16x8 o;
    o[0] = (short)f2b(a.x); o[1] = (short)f2b(a.y);
    o[2] = (short)f2b(a.z); o[3] = (short)f2b(a.w);
    o[4] = (short)f2b(b.x); o[5] = (short)f2b(b.y);
    o[6] = (short)f2b(b.z); o[7] = (short)f2b(b.w);
    *(bf16x8*)(Tb + i) = o;
  } else {
    const int b2 = blockIdx.x - 6144;       // [0,192)
    const int ct = b2 & 3;
    const int kt = (b2 >> 2) % 12;
    const int n  = b2 / 48;
    #pragma unroll
    for (int i = 0; i < 16; ++i) {
      const int kl = i * 4 + (t >> 6), cl = t & 63;
      tile[kl][cl] =
          Wfc[(size_t)n * TD * HID + (size_t)(kt * 64 + kl) * HID + ct * 64 + cl];
    }
    __syncthreads();
    #pragma unroll
    for (int i = 0; i < 16; ++i) {
      const int cl = i * 4 + (t >> 6), kl = t & 63;
      Wtb[(size_t)n * HID * TD + (size_t)(ct * 64 + cl) * TD + kt * 64 + kl] =
          f2b(tile[kl][cl]);
    }
  }
}

// ---- K1: 256x256 MFMA GEMM + fused LN + a1/a2 dots (R4/R8 champion) --------
__global__ __launch_bounds__(512) void k1_mfma(
    const unsigned short* __restrict__ Tb,   // [16384][768] bf16
    const unsigned short* __restrict__ Wtb,  // [4][256][768] bf16 (W^T)
    const float* __restrict__ bfc, const float* __restrict__ lng,
    const float* __restrict__ lnb, const float* __restrict__ aw,
    unsigned short* __restrict__ hb,         // [4][16384][256] bf16
    float* __restrict__ sR, float* __restrict__ sC)
{
  const int n    = blockIdx.x >> 6;
  const int mb   = blockIdx.x & 63;
  const int t    = threadIdx.x;
  const int lane = t & 63;
  const int wq   = __builtin_amdgcn_readfirstlane(t >> 6);
  const int wm   = wq >> 1;          // 0..3  (m quarter)
  const int wn   = wq & 1;           // 0..1  (n half)
  const int cl   = lane & 15;
  const int rg   = lane >> 4;
  const int row0 = mb * 256;

  __shared__ __align__(16) char smem[131072];

  f32x4 acc[4][8];
  #pragma unroll
  for (int mi = 0; mi < 4; ++mi)
    #pragma unroll
    for (int ni = 0; ni < 8; ++ni) acc[mi][ni] = (f32x4){0.f, 0.f, 0.f, 0.f};

  const char* Tg = (const char*)Tb;
  const char* Wg = (const char*)(Wtb + (size_t)n * HID * TD);

  #define STAGE(buf, k0)                                                       \
    do {                                                                       \
      char* base_ = smem + (buf) * 65536;                                      \
      _Pragma("unroll")                                                        \
      for (int i_ = 0; i_ < 4; ++i_) {                                         \
        const int off_ = i_ * 8192 + t * 16;                                   \
        const int r_ = off_ >> 7, kb_ = off_ & 127;                            \
        const int kbs_ = kb_ ^ ((r_ & 7) << 4);                                \
        gll16(Tg + ((size_t)(row0 + r_) * TD + (k0)) * 2 + kbs_, base_ + off_);\
      }                                                                        \
      _Pragma("unroll")                                                        \
      for (int i_ = 0; i_ < 4; ++i_) {                                         \
        const int off_ = i_ * 8192 + t * 16;                                   \
        const int c_ = off_ >> 7, kb_ = off_ & 127;                            \
        const int kbs_ = kb_ ^ ((c_ & 7) << 4);                                \
        gll16(Wg + ((size_t)c_ * TD + (k0)) * 2 + kbs_, base_ + 32768 + off_); \
      }                                                                        \
    } while (0)

  STAGE(0, 0);
  __syncthreads();
  int cur = 0;
  for (int kt = 0; kt < 12; ++kt) {
    if (kt < 11) STAGE(cur ^ 1, (kt + 1) * 64);
    const char* As = smem + cur * 65536;
    const char* Bs = As + 32768;
    #pragma unroll
    for (int ks = 0; ks < 64; ks += 32) {
      bf16x8 av[4], bv[8];
      const int kk2 = (ks + rg * 8) * 2;
      #pragma unroll
      for (int mi = 0; mi < 4; ++mi) {
        const int row = wm * 64 + mi * 16 + cl;
        av[mi] = *(const bf16x8*)(As + row * 128 + (kk2 ^ ((row & 7) << 4)));
      }
      #pragma unroll
      for (int ni = 0; ni < 8; ++ni) {
        const int row = wn * 128 + ni * 16 + cl;
        bv[ni] = *(const bf16x8*)(Bs + row * 128 + (kk2 ^ ((row & 7) << 4)));
      }
      #pragma unroll
      for (int mi = 0; mi < 4; ++mi)
        #pragma unroll
        for (int ni = 0; ni < 8; ++ni)
          acc[mi][ni] = __builtin_amdgcn_mfma_f32_16x16x32_bf16(
              av[mi], bv[ni], acc[mi][ni], 0, 0, 0);
    }
    __syncthreads();
    cur ^= 1;
  }
  #undef STAGE

  // ---- epilogue ----
  unsigned short* hs = (unsigned short*)smem;        // [64][264] per chunk
  float* redS  = (float*)(smem + 36864);             // [256][2]
  float* redS2 = (float*)(smem + 38912);
  float* redP  = (float*)(smem + 40960);
  float* redC  = (float*)(smem + 43008);

  float bfn[8], gvn[8], bvn[8], a1n[8], a2n[8];
  #pragma unroll
  for (int ni = 0; ni < 8; ++ni) {
    const int c = wn * 128 + ni * 16 + cl;
    bfn[ni] = bfc[n * HID + c];
    gvn[ni] = lng[n * HID + c];
    bvn[ni] = lnb[n * HID + c];
    a1n[ni] = aw[n * (2 * HID) + c];
    a2n[ni] = aw[n * (2 * HID) + HID + c];
  }

  #pragma unroll
  for (int mi = 0; mi < 4; ++mi) {
    #pragma unroll
    for (int r = 0; r < 4; ++r) {
      float s = 0.f, s2 = 0.f;
      #pragma unroll
      for (int ni = 0; ni < 8; ++ni) {
        const float x = acc[mi][ni][r] + bfn[ni];
        acc[mi][ni][r] = x;
        s += x; s2 += x * x;
      }
      s = red16(s); s2 = red16(s2);
      if (cl == 0) {
        const int row = wm * 64 + mi * 16 + rg * 4 + r;
        redS [row * 2 + wn] = s;
        redS2[row * 2 + wn] = s2;
      }
    }
  }
  __syncthreads();

  #pragma unroll
  for (int mi = 0; mi < 4; ++mi) {
    #pragma unroll
    for (int r = 0; r < 4; ++r) {
      const int row = wm * 64 + mi * 16 + rg * 4 + r;
      const float st  = redS [row * 2] + redS [row * 2 + 1];
      const float s2t = redS2[row * 2] + redS2[row * 2 + 1];
      const float mu  = st * (1.f / HID);
      const float var = s2t * (1.f / HID) - mu * mu;
      const float rs  = rsqrtf(var + 1e-5f);
      float pr = 0.f, pc = 0.f;
      #pragma unroll
      for (int ni = 0; ni < 8; ++ni) {
        const float hv = (acc[mi][ni][r] - mu) * rs * gvn[ni] + bvn[ni];
        acc[mi][ni][r] = hv;
        pr += hv * a1n[ni]; pc += hv * a2n[ni];
      }
      pr = red16(pr); pc = red16(pc);
      if (cl == 0) { redP[row * 2 + wn] = pr; redC[row * 2 + wn] = pc; }
    }
  }
  __syncthreads();
  if (t < 256) {
    sR[n * RTOT + row0 + t] = (redP[t * 2] + redP[t * 2 + 1]) * L2E;
    sC[n * RTOT + row0 + t] = (redC[t * 2] + redC[t * 2 + 1]) * L2E;
  }

  unsigned short* hgb = hb + ((size_t)n * RTOT + row0) * HID;
  #pragma unroll
  for (int c = 0; c < 4; ++c) {
    #pragma unroll
    for (int ni = 0; ni < 8; ++ni)
      #pragma unroll
      for (int r = 0; r < 4; ++r) {
        const int lr  = wm * 16 + rg * 4 + r;
        const int col = wn * 128 + ni * 16 + cl;
        hs[lr * 264 + col] = f2b(acc[c][ni][r]);
      }
    __syncthreads();
    #pragma unroll
    for (int i = 0; i < 4; ++i) {
      const int idx = i * 4096 + t * 8;
      const int lr = idx >> 8, cc = idx & 255;
      const int grow = (lr >> 4) * 64 + c * 16 + (lr & 15);
      *(bf16x8*)&hgb[(size_t)grow * HID + cc] = *(const bf16x8*)&hs[lr * 264 + cc];
    }
    __syncthreads();
  }
}

// ---- K_TAIL: single cooperative kernel, 512 blocks x 256 thr ---------------
// S1 lse -> S2 colsum+wsum -> S3 cat -> S4 ln -> S5 fcs -> S6 red,
// grid.sync() between stages. Stage bodies = measured R8/R9 kernels.
__global__ __launch_bounds__(256) void k_tail(
    const unsigned short* __restrict__ h, const float* __restrict__ sR,
    const float* __restrict__ sC, const float* __restrict__ ab,
    float* __restrict__ q, float* __restrict__ partial,
    const float* __restrict__ Wcat, float* __restrict__ pcat,
    const float* __restrict__ bcat, const float* __restrict__ lnOg,
    const float* __restrict__ lnOb, float* __restrict__ sent,
    float* __restrict__ out_sent, const float* __restrict__ Wfcs,
    float* __restrict__ pfcs, const float* __restrict__ bfcs,
    float* __restrict__ out)
{
  cg::grid_group grid = cg::this_grid();
  __shared__ __align__(16) char sm[17408];
  const int bid = blockIdx.x;
  const int t   = threadIdx.x;

  // ---- S1: lse (all 512 blocks) ----
  {
    float* rl   = (float*)sm;          // [1024]
    float* r01l = rl + 1024;           // [1024]
    float* red  = r01l + 1024;         // [4]
    const int n  = bid >> 7;
    const int b  = (bid >> 3) & 15;
    const int ic = bid & 7;
    const int base = (n * BB + b) * LL;

    const float4 r4 = ((const float4*)(sR + base))[t];
    ((float4*)rl)[t] = r4;
    float4 r01;
    r01.x = 0.01f * r4.x; r01.y = 0.01f * r4.y;
    r01.z = 0.01f * r4.z; r01.w = 0.01f * r4.w;
    ((float4*)r01l)[t] = r01;
    float tm = fmaxf(fmaxf(r4.x, r4.y), fmaxf(r4.z, r4.w));
    tm = waveReduceMax(tm);
    if ((t & 63) == 0) red[t >> 6] = tm;
    __syncthreads();
    const float rmax = fmaxf(fmaxf(red[0], red[1]), fmaxf(red[2], red[3]));

    const int i  = ic * 128 + (t >> 1);
    const int jh = t & 1;
    const float ci = sC[base + i] + ab[n] * L2E;
    const float m  = lrelu(ci + rmax);
    const float a1 = ci - m;
    const float a2 = 0.01f * ci - m;
    float z0 = 0.f, z1 = 0.f, z2 = 0.f, z3 = 0.f;
    #pragma unroll 4
    for (int j4 = jh * 128; j4 < jh * 128 + 128; ++j4) {
      const float4 rr = ((const float4*)rl)[j4];
      const float4 r0 = ((const float4*)r01l)[j4];
      z0 += EXP2(fmaxf(a1 + rr.x, a2 + r0.x));
      z1 += EXP2(fmaxf(a1 + rr.y, a2 + r0.y));
      z2 += EXP2(fmaxf(a1 + rr.z, a2 + r0.z));
      z3 += EXP2(fmaxf(a1 + rr.w, a2 + r0.w));
    }
    float z = (z0 + z1) + (z2 + z3);
    z += __shfl_xor(z, 1, 64);
    if (!jh) q[base + i] = m + LOG2(z);
  }
  grid.sync();

  // ---- S2: colsum + weighted h-sum (all 512 blocks) ----
  {
    float* cls1 = (float*)sm;                  // [1024]
    float* cls2 = cls1 + 1024;                 // [1024]
    float* wl   = cls2 + 1024;                 // [128]
    float* red2 = wl + 128;                    // [8][256]
    const int n  = bid >> 7;
    const int b  = (bid >> 3) & 15;
    const int jc = bid & 7;
    const int base = (n * BB + b) * LL;

    {
      const float4 c4 = ((const float4*)(sC + base))[t];
      const float4 q4 = ((const float4*)(q + base))[t];
      float4 v1, v2;
      v1.x = c4.x - q4.x; v2.x = 0.01f * c4.x - q4.x;
      v1.y = c4.y - q4.y; v2.y = 0.01f * c4.y - q4.y;
      v1.z = c4.z - q4.z; v2.z = 0.01f * c4.z - q4.z;
      v1.w = c4.w - q4.w; v2.w = 0.01f * c4.w - q4.w;
      ((float4*)cls1)[t] = v1;
      ((float4*)cls2)[t] = v2;
    }
    __syncthreads();

    {
      const int j  = jc * 128 + (t >> 1);
      const int ih = t & 1;
      const float rj  = sR[base + j] + ab[n] * L2E;
      const float r01 = 0.01f * rj;
      float z0 = 0.f, z1 = 0.f, z2 = 0.f, z3 = 0.f;
      #pragma unroll 4
      for (int i4 = ih * 128; i4 < ih * 128 + 128; ++i4) {
        const float4 c1 = ((const float4*)cls1)[i4];
        const float4 c2 = ((const float4*)cls2)[i4];
        z0 += EXP2(fmaxf(c1.x + rj, c2.x + r01));
        z1 += EXP2(fmaxf(c1.y + rj, c2.y + r01));
        z2 += EXP2(fmaxf(c1.z + rj, c2.z + r01));
        z3 += EXP2(fmaxf(c1.w + rj, c2.w + r01));
      }
      float z = (z0 + z1) + (z2 + z3);
      z += __shfl_xor(z, 1, 64);
      if (!ih) wl[t >> 1] = z * (1.f / LL);
    }
    __syncthreads();

    const int jl = t >> 5;
    const int cg2 = t & 31;
    const unsigned short* hp =
        h + ((size_t)n * RTOT + b * LL + jc * 128) * HID + cg2 * 8;
    float a0=0,a1=0,a2=0,a3=0,a4=0,a5=0,a6=0,a7=0;
    #pragma unroll 4
    for (int j = jl; j < 128; j += 8) {
      const bf16x8 v = *(const bf16x8*)(hp + (size_t)j * HID);
      const float w = wl[j];
      a0 = fmaf(w, b2f((unsigned short)v[0]), a0);
      a1 = fmaf(w, b2f((unsigned short)v[1]), a1);
      a2 = fmaf(w, b2f((unsigned short)v[2]), a2);
      a3 = fmaf(w, b2f((unsigned short)v[3]), a3);
      a4 = fmaf(w, b2f((unsigned short)v[4]), a4);
      a5 = fmaf(w, b2f((unsigned short)v[5]), a5);
      a6 = fmaf(w, b2f((unsigned short)v[6]), a6);
      a7 = fmaf(w, b2f((unsigned short)v[7]), a7);
    }
    red2[jl*256 + cg2*8+0]=a0; red2[jl*256 + cg2*8+1]=a1;
    red2[jl*256 + cg2*8+2]=a2; red2[jl*256 + cg2*8+3]=a3;
    red2[jl*256 + cg2*8+4]=a4; red2[jl*256 + cg2*8+5]=a5;
    red2[jl*256 + cg2*8+6]=a6; red2[jl*256 + cg2*8+7]=a7;
    __syncthreads();
    float s = 0.f;
    #pragma unroll
    for (int r = 0; r < 8; ++r) s += red2[r*256 + t];
    partial[((n * BB + b) * 8 + jc) * 256 + t] = s;
  }
  grid.sync();

  // ---- S3: cat partial GEMM (blocks 0..47) ----
  if (bid < 48) {
    float* s = (float*)sm;   // [64][16]
    const int kc = bid / 3;
    const int oc = bid % 3;
    {
      const int kk = t >> 2, b4 = (t & 3) * 4;
      const int n = kc >> 2;
      const int c = (kc & 3) * 64 + kk;
      #pragma unroll
      for (int bi = 0; bi < 4; ++bi) {
        const int b = b4 + bi;
        const float* pb = partial + (size_t)((n * BB + b) * 8) * 256 + c;
        float v = 0.f;
        #pragma unroll
        for (int j = 0; j < 8; ++j) v += pb[j * 256];
        s[kk * 16 + b] = v;
      }
    }
    __syncthreads();
    const int o = oc * 256 + t;
    const float* W = Wcat + (size_t)(kc * 64) * OD + o;
    float acc[BB];
    #pragma unroll
    for (int b = 0; b < BB; ++b) acc[b] = 0.f;
    #pragma unroll 4
    for (int kk = 0; kk < 64; ++kk) {
      const float w = W[(size_t)kk * OD];
      const f32x4 s0 = *(const f32x4*)&s[kk * 16 + 0];
      const f32x4 s1 = *(const f32x4*)&s[kk * 16 + 4];
      const f32x4 s2 = *(const f32x4*)&s[kk * 16 + 8];
      const f32x4 s3 = *(const f32x4*)&s[kk * 16 + 12];
      acc[0]=fmaf(s0.x,w,acc[0]);  acc[1]=fmaf(s0.y,w,acc[1]);
      acc[2]=fmaf(s0.z,w,acc[2]);  acc[3]=fmaf(s0.w,w,acc[3]);
      acc[4]=fmaf(s1.x,w,acc[4]);  acc[5]=fmaf(s1.y,w,acc[5]);
      acc[6]=fmaf(s1.z,w,acc[6]);  acc[7]=fmaf(s1.w,w,acc[7]);
      acc[8]=fmaf(s2.x,w,acc[8]);  acc[9]=fmaf(s2.y,w,acc[9]);
      acc[10]=fmaf(s2.z,w,acc[10]); acc[11]=fmaf(s2.w,w,acc[11]);
      acc[12]=fmaf(s3.x,w,acc[12]); acc[13]=fmaf(s3.y,w,acc[13]);
      acc[14]=fmaf(s3.z,w,acc[14]); acc[15]=fmaf(s3.w,w,acc[15]);
    }
    float* P = pcat + (size_t)(kc * BB) * OD + o;
    #pragma unroll
    for (int b = 0; b < BB; ++b) P[(size_t)b * OD] = acc[b];
  }
  grid.sync();

  // ---- S4: output LN (blocks 0..15) ----
  if (bid < 16) {
    float* red = (float*)sm;   // [4][2]
    const int b = bid;
    float x[3];
    #pragma unroll
    for (int i = 0; i < 3; ++i) {
      const int o = i * 256 + t;
      float v = bcat[o];
      #pragma unroll
      for (int kc = 0; kc < 16; ++kc) v += pcat[(size_t)(kc * BB + b) * OD + o];
      x[i] = v;
    }
    float s  = x[0] + x[1] + x[2];
    float s2 = x[0]*x[0] + x[1]*x[1] + x[2]*x[2];
    s = waveReduceSum(s); s2 = waveReduceSum(s2);
    if ((t & 63) == 0) { red[(t >> 6) * 2] = s; red[(t >> 6) * 2 + 1] = s2; }
    __syncthreads();
    s  = red[0] + red[2] + red[4] + red[6];
    s2 = red[1] + red[3] + red[5] + red[7];
    const float mu  = s * (1.f / OD);
    const float var = s2 * (1.f / OD) - mu * mu;
    const float rs  = rsqrtf(var + 1e-5f);
    #pragma unroll
    for (int i = 0; i < 3; ++i) {
      const int o = i * 256 + t;
      const float y = (x[i] - mu) * rs * lnOg[o] + lnOb[o];
      sent[b * OD + o]     = y;
      out_sent[b * OD + o] = y;
    }
  }
  grid.sync();

  // ---- S5: fcs partial GEMMs (blocks 0..107) ----
  if (bid < 108) {
    float* s = (float*)sm;   // [64][16]
    const int kc = bid / 9;
    const int r  = bid % 9;
    const int i  = r / 3, oc = r % 3;
    {
      const int kk = t >> 2, b4 = (t & 3) * 4;
      #pragma unroll
      for (int bi = 0; bi < 4; ++bi)
        s[kk * 16 + b4 + bi] = sent[(b4 + bi) * OD + kc * 64 + kk];
    }
    __syncthreads();
    const int o = oc * 256 + t;
    const float* W = Wfcs + (size_t)i * OD * OD + (size_t)(kc * 64) * OD + o;
    float acc[BB];
    #pragma unroll
    for (int b = 0; b < BB; ++b) acc[b] = 0.f;
    #pragma unroll 4
    for (int kk = 0; kk < 64; ++kk) {
      const float w = W[(size_t)kk * OD];
      const f32x4 s0 = *(const f32x4*)&s[kk * 16 + 0];
      const f32x4 s1 = *(const f32x4*)&s[kk * 16 + 4];
      const f32x4 s2 = *(const f32x4*)&s[kk * 16 + 8];
      const f32x4 s3 = *(const f32x4*)&s[kk * 16 + 12];
      acc[0]=fmaf(s0.x,w,acc[0]);  acc[1]=fmaf(s0.y,w,acc[1]);
      acc[2]=fmaf(s0.z,w,acc[2]);  acc[3]=fmaf(s0.w,w,acc[3]);
      acc[4]=fmaf(s1.x,w,acc[4]);  acc[5]=fmaf(s1.y,w,acc[5]);
      acc[6]=fmaf(s1.z,w,acc[6]);  acc[7]=fmaf(s1.w,w,acc[7]);
      acc[8]=fmaf(s2.x,w,acc[8]);  acc[9]=fmaf(s2.y,w,acc[9]);
      acc[10]=fmaf(s2.z,w,acc[10]); acc[11]=fmaf(s2.w,w,acc[11]);
      acc[12]=fmaf(s3.x,w,acc[12]); acc[13]=fmaf(s3.y,w,acc[13]);
      acc[14]=fmaf(s3.z,w,acc[14]); acc[15]=fmaf(s3.w,w,acc[15]);
    }
    float* P = pfcs + (size_t)((kc * 3 + i) * BB) * OD + o;
    #pragma unroll
    for (int b = 0; b < BB; ++b) P[(size_t)b * OD] = acc[b];
  }
  grid.sync();

  // ---- S6: final reduce (blocks 0..47) ----
  if (bid < 48) {
    const int i = bid >> 4;
    const int b = bid & 15;
    #pragma unroll
    for (int oc = 0; oc < 3; ++oc) {
      const int o = oc * 256 + t;
      float v = bfcs[i * OD + o];
      #pragma unroll
      for (int kc = 0; kc < 12; ++kc)
        v += pfcs[(size_t)((kc * 3 + i) * BB + b) * OD + o];
      out[i * (BB * OD) + b * OD + o] = v;
    }
  }
}

extern "C" void kernel_launch(void* const* d_in, const int* in_sizes, int n_in,
                              void* d_out, int out_size, void* d_ws, size_t ws_size,
                              hipStream_t stream)
{
  const float* T    = (const float*)d_in[0];
  const float* Wfc  = (const float*)d_in[1];
  const float* bfc  = (const float*)d_in[2];
  const float* lng  = (const float*)d_in[3];
  const float* lnb  = (const float*)d_in[4];
  const float* aw   = (const float*)d_in[5];
  const float* ab   = (const float*)d_in[6];
  const float* Wcat = (const float*)d_in[7];
  const float* bcat = (const float*)d_in[8];
  const float* lnOg = (const float*)d_in[9];
  const float* lnOb = (const float*)d_in[10];
  const float* Wfcs = (const float*)d_in[11];
  const float* bfcs = (const float*)d_in[12];
  float* out = (float*)d_out;

  char* W = (char*)d_ws;
  unsigned short* Tb  = (unsigned short*)W;                 // 25,165,824 B
  unsigned short* Wtb = (unsigned short*)(W + 25165824);    //  1,572,864 B
  unsigned short* hb  = (unsigned short*)(W + 26738688);    // 33,554,432 B
  float* sR      = (float*)(W + 60293120);
  float* sC      = sR + NH * RTOT;
  float* q       = sC + NH * RTOT;
  float* partial = q + NH * RTOT;                           // 131072 f
  float* sent    = partial + NH * BB * 8 * 256;
  float* pcat    = sent + BB * OD;
  float* pfcs    = pcat + 16 * BB * OD;
  float* out_sent = out + 3 * BB * OD;

  kconv   <<<dim3(6336), dim3(256), 0, stream>>>(T, Wfc, Tb, Wtb);
  k1_mfma <<<dim3(256),  dim3(512), 0, stream>>>(Tb, Wtb, bfc, lng, lnb, aw, hb, sR, sC);

  void* args[] = {
    (void*)&hb, (void*)&sR, (void*)&sC, (void*)&ab, (void*)&q, (void*)&partial,
    (void*)&Wcat, (void*)&pcat, (void*)&bcat, (void*)&lnOg, (void*)&lnOb,
    (void*)&sent, (void*)&out_sent, (void*)&Wfcs, (void*)&pfcs, (void*)&bfcs,
    (void*)&out
  };
  hipLaunchCooperativeKernel((const void*)k_tail, dim3(512), dim3(256),
                             args, 0, stream);
}

// Round 14
// 103.297 us; speedup vs baseline: 3.2967x; 3.2967x over previous
//
#include <hip/hip_runtime.h>
#include <math.h>

// MultiHeadGAT fused pipeline, round 14 = round 9 restored (best: 103.3us).
// R13's cooperative-tail regressed 3.3x (grid.sync ~48us each at 512 blocks);
// reverted. k1: R4-champion schedule with fused T->bf16 A-staging. Tail:
// log2-domain softmax. This is the measured plateau of this decomposition.

#define NH   4
#define TD   768
#define HID  256
#define OD   768
#define BB   16
#define LL   1024
#define RTOT (BB*LL)   // 16384 rows per head
#define L2E  1.4426950408889634f

typedef __attribute__((ext_vector_type(8))) short bf16x8;
typedef __attribute__((ext_vector_type(4))) float f32x4;

#if __has_builtin(__builtin_amdgcn_exp2f)
#define EXP2(x) __builtin_amdgcn_exp2f(x)
#else
#define EXP2(x) __expf((x) * 0.6931471805599453f)
#endif
#if __has_builtin(__builtin_amdgcn_logf)
#define LOG2(x) __builtin_amdgcn_logf(x)
#else
#define LOG2(x) (__logf(x) * L2E)
#endif

__device__ __forceinline__ float lrelu(float x) { return fmaxf(x, 0.01f * x); }

__device__ __forceinline__ float waveReduceSum(float v) {
  #pragma unroll
  for (int m = 1; m < 64; m <<= 1) v += __shfl_xor(v, m, 64);
  return v;
}
__device__ __forceinline__ float waveReduceMax(float v) {
  #pragma unroll
  for (int m = 1; m < 64; m <<= 1) v = fmaxf(v, __shfl_xor(v, m, 64));
  return v;
}
__device__ __forceinline__ float red16(float v) {   // reduce across 16-lane group
  v += __shfl_xor(v, 1, 64); v += __shfl_xor(v, 2, 64);
  v += __shfl_xor(v, 4, 64); v += __shfl_xor(v, 8, 64);
  return v;
}

__device__ __forceinline__ unsigned short f2b(float f) {  // f32 -> bf16 RNE
  union { float f; unsigned u; } v; v.f = f;
  unsigned u = v.u;
  return (unsigned short)((u + 0x7fffu + ((u >> 16) & 1u)) >> 16);
}
__device__ __forceinline__ float b2f(unsigned short h) {
  union { unsigned u; float f; } v; v.u = ((unsigned)h) << 16;
  return v.f;
}
// packed f32x2 -> bf16x2 (RNE), single VALU op
__device__ __forceinline__ unsigned cvtpk(float lo, float hi) {
  unsigned r;
  asm("v_cvt_pk_bf16_f32 %0, %1, %2" : "=v"(r) : "v"(lo), "v"(hi));
  return r;
}

__device__ __forceinline__ void gll16(const void* g, void* l) {
  __builtin_amdgcn_global_load_lds(
      (const __attribute__((address_space(1))) unsigned int*)g,
      (__attribute__((address_space(3))) unsigned int*)l, 16, 0, 0);
}

// ---- conversion kernel: W only ---------------------------------------------
// Wfc fp32 [n][k=768][c=256] -> bf16 transposed Wt [n][c=256][k=768]
__global__ __launch_bounds__(256) void kconv_w(const float* __restrict__ src,
                                               unsigned short* __restrict__ dst) {
  __shared__ float tile[64][65];
  const int t  = threadIdx.x;
  const int ct = blockIdx.x & 3;
  const int kt = (blockIdx.x >> 2) % 12;
  const int n  = blockIdx.x / 48;
  #pragma unroll
  for (int i = 0; i < 16; ++i) {
    const int kl = i * 4 + (t >> 6), cl = t & 63;
    tile[kl][cl] =
        src[(size_t)n * TD * HID + (size_t)(kt * 64 + kl) * HID + ct * 64 + cl];
  }
  __syncthreads();
  #pragma unroll
  for (int i = 0; i < 16; ++i) {
    const int cl = i * 4 + (t >> 6), kl = t & 63;
    dst[(size_t)n * HID * TD + (size_t)(ct * 64 + cl) * TD + kt * 64 + kl] =
        f2b(tile[kl][cl]);
  }
}

// ---- K1: 256x256 MFMA GEMM + fused T-conversion + LN + a1/a2 dots ----------
// grid = 4 heads x 64 m-blocks; 8 waves (2n x 4m), wave tile 64 rows x 128 cols.
// LDS: dbuf x (As[256][64] | Bs[256][64]) bf16 = 2 x 64KB = 128KB.
// A: reg-staged from fp32 T (prefetched 1 K-step ahead), cvt_pk, swizzled
//    ds_write_b128. B: global_load_lds, pre-swizzled source.
// Swizzle: LDS[r][kb ^ ((r&7)<<4)] = G[r][kb]; ds_read applies same XOR.
__global__ __launch_bounds__(512) void k1_mfma(
    const float* __restrict__ T,             // [16384][768] fp32
    const unsigned short* __restrict__ Wtb,  // [4][256][768] bf16 (W^T)
    const float* __restrict__ bfc, const float* __restrict__ lng,
    const float* __restrict__ lnb, const float* __restrict__ aw,
    unsigned short* __restrict__ hb,         // [4][16384][256] bf16
    float* __restrict__ sR, float* __restrict__ sC)
{
  const int n    = blockIdx.x >> 6;
  const int mb   = blockIdx.x & 63;
  const int t    = threadIdx.x;
  const int lane = t & 63;
  const int wq   = __builtin_amdgcn_readfirstlane(t >> 6);
  const int wm   = wq >> 1;          // 0..3  (m quarter)
  const int wn   = wq & 1;           // 0..1  (n half)
  const int cl   = lane & 15;
  const int rg   = lane >> 4;
  const int row0 = mb * 256;

  __shared__ __align__(16) char smem[131072];

  f32x4 acc[4][8];
  #pragma unroll
  for (int mi = 0; mi < 4; ++mi)
    #pragma unroll
    for (int ni = 0; ni < 8; ++ni) acc[mi][ni] = (f32x4){0.f, 0.f, 0.f, 0.f};

  const char* Wg = (const char*)(Wtb + (size_t)n * HID * TD);

  // A reg-stage: 4 rows/thread (row = j*64 + t>>3), 8 fp32 (kcol (t&7)*8)
  #define LDA(r, k0)                                                           \
    do {                                                                       \
      _Pragma("unroll")                                                        \
      for (int j_ = 0; j_ < 4; ++j_) {                                         \
        const float* p_ = T + (size_t)(row0 + j_ * 64 + (t >> 3)) * TD +       \
                          (k0) + (t & 7) * 8;                                  \
        r[2 * j_]     = *(const float4*)p_;                                    \
        r[2 * j_ + 1] = *(const float4*)(p_ + 4);                              \
      }                                                                        \
    } while (0)

  // A cvt_pk + swizzled ds_write_b128 into buf
  #define WRA(buf, r)                                                          \
    do {                                                                       \
      char* ab_ = smem + (buf) * 65536;                                        \
      _Pragma("unroll")                                                        \
      for (int j_ = 0; j_ < 4; ++j_) {                                         \
        const int row_ = j_ * 64 + (t >> 3);                                   \
        const int kb_  = (t & 7) * 16;                                         \
        uint4 p_;                                                              \
        p_.x = cvtpk(r[2 * j_].x,     r[2 * j_].y);                            \
        p_.y = cvtpk(r[2 * j_].z,     r[2 * j_].w);                            \
        p_.z = cvtpk(r[2 * j_ + 1].x, r[2 * j_ + 1].y);                        \
        p_.w = cvtpk(r[2 * j_ + 1].z, r[2 * j_ + 1].w);                        \
        *(uint4*)(ab_ + row_ * 128 + (kb_ ^ ((row_ & 7) << 4))) = p_;          \
      }                                                                        \
    } while (0)

  // B stage: 32KB via global_load_lds, pre-swizzled source
  #define STAGE_B(buf, k0)                                                     \
    do {                                                                       \
      char* bb_ = smem + (buf) * 65536 + 32768;                                \
      _Pragma("unroll")                                                        \
      for (int i_ = 0; i_ < 4; ++i_) {                                         \
        const int off_ = i_ * 8192 + t * 16;                                   \
        const int c_ = off_ >> 7, kb_ = off_ & 127;                            \
        const int kbs_ = kb_ ^ ((c_ & 7) << 4);                                \
        gll16(Wg + ((size_t)c_ * TD + (k0)) * 2 + kbs_, bb_ + off_);           \
      }                                                                        \
    } while (0)

  float4 rA[8];
  // prologue: tile0 staged (A written, B issued), tile1 A in regs
  LDA(rA, 0);
  STAGE_B(0, 0);
  WRA(0, rA);
  LDA(rA, 64);
  __syncthreads();                 // drains vmcnt (B0) + lgkm (A0 writes)

  int cur = 0;
  for (int kt = 0; kt < 12; ++kt) {
    if (kt < 11) {
      STAGE_B(cur ^ 1, (kt + 1) * 64);   // async B prefetch
      WRA(cur ^ 1, rA);                  // A tile kt+1 from regs
      if (kt < 10) LDA(rA, (kt + 2) * 64);   // A tile kt+2 into regs
    }
    const char* As = smem + cur * 65536;
    const char* Bs = As + 32768;
    #pragma unroll
    for (int ks = 0; ks < 64; ks += 32) {
      bf16x8 av[4], bv[8];
      const int kk2 = (ks + rg * 8) * 2;
      #pragma unroll
      for (int mi = 0; mi < 4; ++mi) {
        const int row = wm * 64 + mi * 16 + cl;
        av[mi] = *(const bf16x8*)(As + row * 128 + (kk2 ^ ((row & 7) << 4)));
      }
      #pragma unroll
      for (int ni = 0; ni < 8; ++ni) {
        const int row = wn * 128 + ni * 16 + cl;
        bv[ni] = *(const bf16x8*)(Bs + row * 128 + (kk2 ^ ((row & 7) << 4)));
      }
      #pragma unroll
      for (int mi = 0; mi < 4; ++mi)
        #pragma unroll
        for (int ni = 0; ni < 8; ++ni)
          acc[mi][ni] = __builtin_amdgcn_mfma_f32_16x16x32_bf16(
              av[mi], bv[ni], acc[mi][ni], 0, 0, 0);
    }
    __syncthreads();               // reads of cur done + prefetch landed
    cur ^= 1;
  }
  #undef LDA
  #undef WRA
  #undef STAGE_B

  // ---- epilogue ----
  unsigned short* hs = (unsigned short*)smem;        // [64][264] per chunk
  float* redS  = (float*)(smem + 36864);             // [256][2]
  float* redS2 = (float*)(smem + 38912);
  float* redP  = (float*)(smem + 40960);
  float* redC  = (float*)(smem + 43008);

  float bfn[8], gvn[8], bvn[8], a1n[8], a2n[8];
  #pragma unroll
  for (int ni = 0; ni < 8; ++ni) {
    const int c = wn * 128 + ni * 16 + cl;
    bfn[ni] = bfc[n * HID + c];
    gvn[ni] = lng[n * HID + c];
    bvn[ni] = lnb[n * HID + c];
    a1n[ni] = aw[n * (2 * HID) + c];
    a2n[ni] = aw[n * (2 * HID) + HID + c];
  }

  // E1: per-row sum / sumsq (this wave covers half the row -> LDS combine)
  #pragma unroll
  for (int mi = 0; mi < 4; ++mi) {
    #pragma unroll
    for (int r = 0; r < 4; ++r) {
      float s = 0.f, s2 = 0.f;
      #pragma unroll
      for (int ni = 0; ni < 8; ++ni) {
        const float x = acc[mi][ni][r] + bfn[ni];
        acc[mi][ni][r] = x;
        s += x; s2 += x * x;
      }
      s = red16(s); s2 = red16(s2);
      if (cl == 0) {
        const int row = wm * 64 + mi * 16 + rg * 4 + r;
        redS [row * 2 + wn] = s;
        redS2[row * 2 + wn] = s2;
      }
    }
  }
  __syncthreads();

  // E2: normalize, a1/a2 dots
  #pragma unroll
  for (int mi = 0; mi < 4; ++mi) {
    #pragma unroll
    for (int r = 0; r < 4; ++r) {
      const int row = wm * 64 + mi * 16 + rg * 4 + r;
      const float st  = redS [row * 2] + redS [row * 2 + 1];
      const float s2t = redS2[row * 2] + redS2[row * 2 + 1];
      const float mu  = st * (1.f / HID);
      const float var = s2t * (1.f / HID) - mu * mu;
      const float rs  = rsqrtf(var + 1e-5f);
      float pr = 0.f, pc = 0.f;
      #pragma unroll
      for (int ni = 0; ni < 8; ++ni) {
        const float hv = (acc[mi][ni][r] - mu) * rs * gvn[ni] + bvn[ni];
        acc[mi][ni][r] = hv;
        pr += hv * a1n[ni]; pc += hv * a2n[ni];
      }
      pr = red16(pr); pc = red16(pc);
      if (cl == 0) { redP[row * 2 + wn] = pr; redC[row * 2 + wn] = pc; }
    }
  }
  __syncthreads();
  if (t < 256) {
    // pre-scale by log2(e): downstream softmax runs in log2 domain
    sR[n * RTOT + row0 + t] = (redP[t * 2] + redP[t * 2 + 1]) * L2E;
    sC[n * RTOT + row0 + t] = (redC[t * 2] + redC[t * 2 + 1]) * L2E;
  }

  // E3: h store via LDS bounce, 4 chunks (chunk c = fragment-row group mi=c)
  unsigned short* hgb = hb + ((size_t)n * RTOT + row0) * HID;
  #pragma unroll
  for (int c = 0; c < 4; ++c) {
    #pragma unroll
    for (int ni = 0; ni < 8; ++ni)
      #pragma unroll
      for (int r = 0; r < 4; ++r) {
        const int lr  = wm * 16 + rg * 4 + r;
        const int col = wn * 128 + ni * 16 + cl;
        hs[lr * 264 + col] = f2b(acc[c][ni][r]);
      }
    __syncthreads();
    #pragma unroll
    for (int i = 0; i < 4; ++i) {
      const int idx = i * 4096 + t * 8;
      const int lr = idx >> 8, cc = idx & 255;
      const int grow = (lr >> 4) * 64 + c * 16 + (lr & 15);
      *(bf16x8*)&hgb[(size_t)grow * HID + cc] = *(const bf16x8*)&hs[lr * 264 + cc];
    }
    __syncthreads();
  }
}

// K2a (log2 domain): q'[i] = m' + log2(sum_j 2^(lrelu(c'_i + r'_j) - m'))
__global__ __launch_bounds__(256) void k2_lse(
    const float* __restrict__ sR, const float* __restrict__ sC,
    const float* __restrict__ ab, float* __restrict__ q)
{
  const int n  = blockIdx.x >> 7;
  const int b  = (blockIdx.x >> 3) & 15;
  const int ic = blockIdx.x & 7;
  const int t  = threadIdx.x;
  const int base = (n * BB + b) * LL;

  __shared__ float rl[LL];
  __shared__ float r01l[LL];
  __shared__ float red[4];

  const float4 r4 = ((const float4*)(sR + base))[t];
  ((float4*)rl)[t] = r4;
  float4 r01;
  r01.x = 0.01f * r4.x; r01.y = 0.01f * r4.y;
  r01.z = 0.01f * r4.z; r01.w = 0.01f * r4.w;
  ((float4*)r01l)[t] = r01;
  float tm = fmaxf(fmaxf(r4.x, r4.y), fmaxf(r4.z, r4.w));
  tm = waveReduceMax(tm);
  if ((t & 63) == 0) red[t >> 6] = tm;
  __syncthreads();
  const float rmax = fmaxf(fmaxf(red[0], red[1]), fmaxf(red[2], red[3]));

  const int i  = ic * 128 + (t >> 1);
  const int jh = t & 1;
  const float ci = sC[base + i] + ab[n] * L2E;
  const float m  = lrelu(ci + rmax);
  const float a1 = ci - m;
  const float a2 = 0.01f * ci - m;
  float z0 = 0.f, z1 = 0.f, z2 = 0.f, z3 = 0.f;
  #pragma unroll 4
  for (int j4 = jh * 128; j4 < jh * 128 + 128; ++j4) {
    const float4 rr = ((const float4*)rl)[j4];
    const float4 r0 = ((const float4*)r01l)[j4];
    z0 += EXP2(fmaxf(a1 + rr.x, a2 + r0.x));
    z1 += EXP2(fmaxf(a1 + rr.y, a2 + r0.y));
    z2 += EXP2(fmaxf(a1 + rr.z, a2 + r0.z));
    z3 += EXP2(fmaxf(a1 + rr.w, a2 + r0.w));
  }
  float z = (z0 + z1) + (z2 + z3);
  z += __shfl_xor(z, 1, 64);
  if (!jh) q[base + i] = m + LOG2(z);
}

// K23 (log2 domain): fused colsum + weighted h-sum.
__global__ __launch_bounds__(256) void k23_colw(
    const unsigned short* __restrict__ h, const float* __restrict__ sR,
    const float* __restrict__ sC, const float* __restrict__ ab,
    const float* __restrict__ q, float* __restrict__ partial)
{
  const int n  = blockIdx.x >> 7;
  const int b  = (blockIdx.x >> 3) & 15;
  const int jc = blockIdx.x & 7;
  const int t  = threadIdx.x;
  const int base = (n * BB + b) * LL;

  __shared__ float cls1[LL];
  __shared__ float cls2[LL];
  __shared__ float wl[128];
  __shared__ float red2[8][256];

  {
    const float4 c4 = ((const float4*)(sC + base))[t];
    const float4 q4 = ((const float4*)(q + base))[t];
    float4 v1, v2;
    v1.x = c4.x - q4.x; v2.x = 0.01f * c4.x - q4.x;
    v1.y = c4.y - q4.y; v2.y = 0.01f * c4.y - q4.y;
    v1.z = c4.z - q4.z; v2.z = 0.01f * c4.z - q4.z;
    v1.w = c4.w - q4.w; v2.w = 0.01f * c4.w - q4.w;
    ((float4*)cls1)[t] = v1;
    ((float4*)cls2)[t] = v2;
  }
  __syncthreads();

  {
    const int j  = jc * 128 + (t >> 1);
    const int ih = t & 1;
    const float rj  = sR[base + j] + ab[n] * L2E;
    const float r01 = 0.01f * rj;
    float z0 = 0.f, z1 = 0.f, z2 = 0.f, z3 = 0.f;
    #pragma unroll 4
    for (int i4 = ih * 128; i4 < ih * 128 + 128; ++i4) {
      const float4 c1 = ((const float4*)cls1)[i4];
      const float4 c2 = ((const float4*)cls2)[i4];
      z0 += EXP2(fmaxf(c1.x + rj, c2.x + r01));
      z1 += EXP2(fmaxf(c1.y + rj, c2.y + r01));
      z2 += EXP2(fmaxf(c1.z + rj, c2.z + r01));
      z3 += EXP2(fmaxf(c1.w + rj, c2.w + r01));
    }
    float z = (z0 + z1) + (z2 + z3);
    z += __shfl_xor(z, 1, 64);
    if (!ih) wl[t >> 1] = z * (1.f / LL);
  }
  __syncthreads();

  const int jl = t >> 5;
  const int cg = t & 31;
  const unsigned short* hp =
      h + ((size_t)n * RTOT + b * LL + jc * 128) * HID + cg * 8;
  float a0=0,a1=0,a2=0,a3=0,a4=0,a5=0,a6=0,a7=0;
  #pragma unroll 4
  for (int j = jl; j < 128; j += 8) {
    const bf16x8 v = *(const bf16x8*)(hp + (size_t)j * HID);
    const float w = wl[j];
    a0 = fmaf(w, b2f((unsigned short)v[0]), a0);
    a1 = fmaf(w, b2f((unsigned short)v[1]), a1);
    a2 = fmaf(w, b2f((unsigned short)v[2]), a2);
    a3 = fmaf(w, b2f((unsigned short)v[3]), a3);
    a4 = fmaf(w, b2f((unsigned short)v[4]), a4);
    a5 = fmaf(w, b2f((unsigned short)v[5]), a5);
    a6 = fmaf(w, b2f((unsigned short)v[6]), a6);
    a7 = fmaf(w, b2f((unsigned short)v[7]), a7);
  }
  red2[jl][cg*8+0]=a0; red2[jl][cg*8+1]=a1; red2[jl][cg*8+2]=a2; red2[jl][cg*8+3]=a3;
  red2[jl][cg*8+4]=a4; red2[jl][cg*8+5]=a5; red2[jl][cg*8+6]=a6; red2[jl][cg*8+7]=a7;
  __syncthreads();
  float s = 0.f;
  #pragma unroll
  for (int r = 0; r < 8; ++r) s += red2[r][t];
  partial[((n * BB + b) * 8 + jc) * 256 + t] = s;
}

// K4a: K-split partial GEMM (sent_raw reduce folded into staging)
__global__ __launch_bounds__(256) void k4_cat(
    const float* __restrict__ partial, const float* __restrict__ Wcat,
    float* __restrict__ pcat)
{
  const int kc = blockIdx.x / 3;
  const int oc = blockIdx.x % 3;
  const int t  = threadIdx.x;
  __shared__ float s[64][16];
  {
    const int kk = t >> 2, b4 = (t & 3) * 4;
    const int n = kc >> 2;
    const int c = (kc & 3) * 64 + kk;
    #pragma unroll
    for (int bi = 0; bi < 4; ++bi) {
      const int b = b4 + bi;
      const float* pb = partial + (size_t)((n * BB + b) * 8) * 256 + c;
      float v = 0.f;
      #pragma unroll
      for (int j = 0; j < 8; ++j) v += pb[j * 256];
      s[kk][b] = v;
    }
  }
  __syncthreads();
  const int o = oc * 256 + t;
  const float* W = Wcat + (size_t)(kc * 64) * OD + o;
  float acc[BB];
  #pragma unroll
  for (int b = 0; b < BB; ++b) acc[b] = 0.f;
  #pragma unroll 4
  for (int kk = 0; kk < 64; ++kk) {
    const float w = W[(size_t)kk * OD];
    const f32x4 s0 = *(const f32x4*)&s[kk][0];
    const f32x4 s1 = *(const f32x4*)&s[kk][4];
    const f32x4 s2 = *(const f32x4*)&s[kk][8];
    const f32x4 s3 = *(const f32x4*)&s[kk][12];
    acc[0]=fmaf(s0.x,w,acc[0]);  acc[1]=fmaf(s0.y,w,acc[1]);
    acc[2]=fmaf(s0.z,w,acc[2]);  acc[3]=fmaf(s0.w,w,acc[3]);
    acc[4]=fmaf(s1.x,w,acc[4]);  acc[5]=fmaf(s1.y,w,acc[5]);
    acc[6]=fmaf(s1.z,w,acc[6]);  acc[7]=fmaf(s1.w,w,acc[7]);
    acc[8]=fmaf(s2.x,w,acc[8]);  acc[9]=fmaf(s2.y,w,acc[9]);
    acc[10]=fmaf(s2.z,w,acc[10]); acc[11]=fmaf(s2.w,w,acc[11]);
    acc[12]=fmaf(s3.x,w,acc[12]); acc[13]=fmaf(s3.y,w,acc[13]);
    acc[14]=fmaf(s3.z,w,acc[14]); acc[15]=fmaf(s3.w,w,acc[15]);
  }
  float* P = pcat + (size_t)(kc * BB) * OD + o;
  #pragma unroll
  for (int b = 0; b < BB; ++b) P[(size_t)b * OD] = acc[b];
}

// K4b: sent = LN(bcat + sum_kc pcat)
__global__ __launch_bounds__(256) void k4_ln(
    const float* __restrict__ pcat, const float* __restrict__ bcat,
    const float* __restrict__ g, const float* __restrict__ be,
    float* __restrict__ sent, float* __restrict__ out_sent)
{
  const int b = blockIdx.x;
  const int t = threadIdx.x;
  __shared__ float red[4][2];
  float x[3];
  #pragma unroll
  for (int i = 0; i < 3; ++i) {
    const int o = i * 256 + t;
    float v = bcat[o];
    #pragma unroll
    for (int kc = 0; kc < 16; ++kc) v += pcat[(size_t)(kc * BB + b) * OD + o];
    x[i] = v;
  }
  float s  = x[0] + x[1] + x[2];
  float s2 = x[0]*x[0] + x[1]*x[1] + x[2]*x[2];
  s = waveReduceSum(s); s2 = waveReduceSum(s2);
  if ((t & 63) == 0) { red[t >> 6][0] = s; red[t >> 6][1] = s2; }
  __syncthreads();
  s  = red[0][0] + red[1][0] + red[2][0] + red[3][0];
  s2 = red[0][1] + red[1][1] + red[2][1] + red[3][1];
  const float mu  = s * (1.f / OD);
  const float var = s2 * (1.f / OD) - mu * mu;
  const float rs  = rsqrtf(var + 1e-5f);
  #pragma unroll
  for (int i = 0; i < 3; ++i) {
    const int o = i * 256 + t;
    const float y = (x[i] - mu) * rs * g[o] + be[o];
    sent[b * OD + o]     = y;
    out_sent[b * OD + o] = y;
  }
}

// K4c: K-split partials for the three output FCs.
__global__ __launch_bounds__(256) void k4_fcs(
    const float* __restrict__ sent, const float* __restrict__ Wfcs,
    float* __restrict__ pfcs)
{
  const int kc = blockIdx.x / 9;
  const int r  = blockIdx.x % 9;
  const int i  = r / 3, oc = r % 3;
  const int t  = threadIdx.x;
  __shared__ float s[64][16];
  {
    const int kk = t >> 2, b4 = (t & 3) * 4;
    #pragma unroll
    for (int bi = 0; bi < 4; ++bi)
      s[kk][b4 + bi] = sent[(b4 + bi) * OD + kc * 64 + kk];
  }
  __syncthreads();
  const int o = oc * 256 + t;
  const float* W = Wfcs + (size_t)i * OD * OD + (size_t)(kc * 64) * OD + o;
  float acc[BB];
  #pragma unroll
  for (int b = 0; b < BB; ++b) acc[b] = 0.f;
  #pragma unroll 4
  for (int kk = 0; kk < 64; ++kk) {
    const float w = W[(size_t)kk * OD];
    const f32x4 s0 = *(const f32x4*)&s[kk][0];
    const f32x4 s1 = *(const f32x4*)&s[kk][4];
    const f32x4 s2 = *(const f32x4*)&s[kk][8];
    const f32x4 s3 = *(const f32x4*)&s[kk][12];
    acc[0]=fmaf(s0.x,w,acc[0]);  acc[1]=fmaf(s0.y,w,acc[1]);
    acc[2]=fmaf(s0.z,w,acc[2]);  acc[3]=fmaf(s0.w,w,acc[3]);
    acc[4]=fmaf(s1.x,w,acc[4]);  acc[5]=fmaf(s1.y,w,acc[5]);
    acc[6]=fmaf(s1.z,w,acc[6]);  acc[7]=fmaf(s1.w,w,acc[7]);
    acc[8]=fmaf(s2.x,w,acc[8]);  acc[9]=fmaf(s2.y,w,acc[9]);
    acc[10]=fmaf(s2.z,w,acc[10]); acc[11]=fmaf(s2.w,w,acc[11]);
    acc[12]=fmaf(s3.x,w,acc[12]); acc[13]=fmaf(s3.y,w,acc[13]);
    acc[14]=fmaf(s3.z,w,acc[14]); acc[15]=fmaf(s3.w,w,acc[15]);
  }
  float* P = pfcs + (size_t)((kc * 3 + i) * BB) * OD + o;
  #pragma unroll
  for (int b = 0; b < BB; ++b) P[(size_t)b * OD] = acc[b];
}

// K4d: out[i][b][o] = bfcs[i,o] + sum_kc pfcs
__global__ __launch_bounds__(256) void k4_red(
    const float* __restrict__ pfcs, const float* __restrict__ bfcs,
    float* __restrict__ out)
{
  const int i = blockIdx.x >> 4;
  const int b = blockIdx.x & 15;
  const int t = threadIdx.x;
  #pragma unroll
  for (int oc = 0; oc < 3; ++oc) {
    const int o = oc * 256 + t;
    float v = bfcs[i * OD + o];
    #pragma unroll
    for (int kc = 0; kc < 12; ++kc)
      v += pfcs[(size_t)((kc * 3 + i) * BB + b) * OD + o];
    out[i * (BB * OD) + b * OD + o] = v;
  }
}

extern "C" void kernel_launch(void* const* d_in, const int* in_sizes, int n_in,
                              void* d_out, int out_size, void* d_ws, size_t ws_size,
                              hipStream_t stream)
{
  const float* T    = (const float*)d_in[0];
  const float* Wfc  = (const float*)d_in[1];
  const float* bfc  = (const float*)d_in[2];
  const float* lng  = (const float*)d_in[3];
  const float* lnb  = (const float*)d_in[4];
  const float* aw   = (const float*)d_in[5];
  const float* ab   = (const float*)d_in[6];
  const float* Wcat = (const float*)d_in[7];
  const float* bcat = (const float*)d_in[8];
  const float* lnOg = (const float*)d_in[9];
  const float* lnOb = (const float*)d_in[10];
  const float* Wfcs = (const float*)d_in[11];
  const float* bfcs = (const float*)d_in[12];
  float* out = (float*)d_out;

  char* W = (char*)d_ws;
  unsigned short* Wtb = (unsigned short*)W;                 //  1,572,864 B
  unsigned short* hb  = (unsigned short*)(W + 1572864);     // 33,554,432 B
  float* sR      = (float*)(W + 35127296);
  float* sC      = sR + NH * RTOT;
  float* q       = sC + NH * RTOT;
  float* partial = q + NH * RTOT;                           // 131072 f
  float* sent    = partial + NH * BB * 8 * 256;
  float* pcat    = sent + BB * OD;
  float* pfcs    = pcat + 16 * BB * OD;

  kconv_w <<<dim3(192),  dim3(256), 0, stream>>>(Wfc, Wtb);
  k1_mfma <<<dim3(256),  dim3(512), 0, stream>>>(T, Wtb, bfc, lng, lnb, aw, hb, sR, sC);
  k2_lse  <<<dim3(512),  dim3(256), 0, stream>>>(sR, sC, ab, q);
  k23_colw<<<dim3(512),  dim3(256), 0, stream>>>(hb, sR, sC, ab, q, partial);
  k4_cat  <<<dim3(48),   dim3(256), 0, stream>>>(partial, Wcat, pcat);
  k4_ln   <<<dim3(16),   dim3(256), 0, stream>>>(pcat, bcat, lnOg, lnOb, sent, out + 3 * BB * OD);
  k4_fcs  <<<dim3(108),  dim3(256), 0, stream>>>(sent, Wfcs, pfcs);
  k4_red  <<<dim3(48),   dim3(256), 0, stream>>>(pfcs, bfcs, out);
}